// Round 1
// baseline (707.945 us; speedup 1.0000x reference)
//
#include <hip/hip_runtime.h>

// SoftmaxMatcher on MI355X.
// B=4 pairs: src frame 2b (keypoints), tgt frame 2b+1 (dense).
// s[b][n][m] = <src_norm[b,:,n], tgt_norm[b,:,m]>  (K=128)
// p = softmax(s/0.01) over m; coords = soft-argmax; then bilinear sample.
//
// Numerics: s<=1 (normalized) -> fixed-shift softmax e=exp2((s-1)*144.2695),
// no row max needed. GEMM in 3-term bf16 split (hi*hi+hi*lo+lo*hi) ~ f32
// accuracy (needed: coords to <<1px because match_weights samples random maps).

typedef short  v8s __attribute__((ext_vector_type(8)));
typedef unsigned short v8u __attribute__((ext_vector_type(8)));
typedef float  v4f __attribute__((ext_vector_type(4)));

#define EXP2_SCALE 144.269504088896f   // 1/(0.01*ln2)

// ---- workspace layout (bytes) ----
static const size_t O_AHI  = 0;                       // ushort[4*512*128]   512KB
static const size_t O_ALO  = O_AHI  + 262144*2;       // 512KB
static const size_t O_SRCN = O_ALO  + 262144*2;       // float[4*512*128]    1MB
static const size_t O_BHI  = O_SRCN + 262144*4;       // ushort[4*65536*128] 64MB
static const size_t O_BLO  = O_BHI  + 33554432ull*2;  // 64MB
static const size_t O_PART = O_BLO  + 33554432ull*2;  // float[2048*32*4*3]  3MB
static const size_t O_ROWS = O_PART + 2048ull*32*4*3*4; // float4[2048]      32KB
// total ~133 MB

static __device__ inline unsigned short f2bf(float x) {
    unsigned u = __float_as_uint(x);
    u = u + 0x7FFFu + ((u >> 16) & 1u);   // RNE
    return (unsigned short)(u >> 16);
}
static __device__ inline float bf2f(unsigned short h) {
    return __uint_as_float(((unsigned)h) << 16);
}

// ---------------- prep: normalize src keypoint descs, bf16 hi/lo, [row][k] ----
__global__ void __launch_bounds__(256) k_prep_src(const float* __restrict__ kd,
                                                  float* __restrict__ srcN,
                                                  unsigned short* __restrict__ Ahi,
                                                  unsigned short* __restrict__ Alo) {
    int gw = blockIdx.x * 4 + (threadIdx.x >> 6);  // 0..2047 = b*512+n
    int l  = threadIdx.x & 63;
    int b  = gw >> 9, n = gw & 511;
    const float* base = kd + (size_t)(2 * b) * 128 * 512;
    float x0 = base[l * 512 + n];
    float x1 = base[(l + 64) * 512 + n];
    float ss = x0 * x0 + x1 * x1;
#pragma unroll
    for (int m = 1; m < 64; m <<= 1) ss += __shfl_xor(ss, m, 64);
    float inv = 1.0f / fmaxf(sqrtf(ss), 1e-12f);
    float xn0 = x0 * inv, xn1 = x1 * inv;
    int ob = gw * 128;
    srcN[ob + l] = xn0;  srcN[ob + l + 64] = xn1;
    unsigned short h0 = f2bf(xn0), h1 = f2bf(xn1);
    Ahi[ob + l] = h0;        Ahi[ob + l + 64] = h1;
    Alo[ob + l] = f2bf(xn0 - bf2f(h0));
    Alo[ob + l + 64] = f2bf(xn1 - bf2f(h1));
}

// ---------------- prep: normalize tgt dense descs, transpose to [m][k], hi/lo ----
__global__ void __launch_bounds__(256, 2) k_prep_tgt(const float* __restrict__ dd,
                                                     unsigned short* __restrict__ Bhi,
                                                     unsigned short* __restrict__ Blo) {
    int t = blockIdx.x * 256 + threadIdx.x;   // 0..262143
    int b = t >> 16;
    int p = t & 65535;
    const float* src = dd + (size_t)(2 * b + 1) * 128 * 65536 + p;
    float v[128];
    float ss = 0.f;
#pragma unroll
    for (int c = 0; c < 128; ++c) { float x = src[(size_t)c * 65536]; v[c] = x; ss += x * x; }
    float inv = 1.0f / fmaxf(sqrtf(ss), 1e-12f);
    size_t ob = (size_t)t * 128;   // t == b*65536+p
#pragma unroll
    for (int c8 = 0; c8 < 16; ++c8) {
        v8u h8, l8;
#pragma unroll
        for (int j = 0; j < 8; ++j) {
            float xn = v[c8 * 8 + j] * inv;
            unsigned short h = f2bf(xn);
            h8[j] = h;
            l8[j] = f2bf(xn - bf2f(h));
        }
        *(v8u*)(Bhi + ob + c8 * 8) = h8;
        *(v8u*)(Blo + ob + c8 * 8) = l8;
    }
}

// ---------------- pass A: GEMM -> per-row {sum e, sum e*u, sum e*v} partials ----
// grid 512 = 16 slots (b,nt) x 32 gm;  block 512 thr = 8 waves (2 wm x 4 wn)
__global__ void __launch_bounds__(512, 2) k_pass_a(const unsigned short* __restrict__ Ahi,
                                                   const unsigned short* __restrict__ Alo,
                                                   const unsigned short* __restrict__ Bhi,
                                                   const unsigned short* __restrict__ Blo,
                                                   float* __restrict__ part) {
    int tid = threadIdx.x;
    int l = tid & 63, wid = tid >> 6;
    int wm = wid >> 2, wn = wid & 3;
    int l15 = l & 15, l16 = l >> 4;
    int slot = blockIdx.x >> 5, gm = blockIdx.x & 31;
    int b = slot >> 2, nt = slot & 3;
    int row0 = nt * 128 + wm * 64;

    const unsigned short* pAh = Ahi + ((b * 512 + row0 + l15) * 128 + l16 * 8);
    const unsigned short* pAl = Alo + ((b * 512 + row0 + l15) * 128 + l16 * 8);
    const unsigned short* pBh = Bhi + ((b * 65536 + wn * 64 + l15) * 128 + l16 * 8);
    const unsigned short* pBl = Blo + ((b * 65536 + wn * 64 + l15) * 128 + l16 * 8);

    float se[16], seu[16], sev[16];
#pragma unroll
    for (int s = 0; s < 16; ++s) { se[s] = 0.f; seu[s] = 0.f; sev[s] = 0.f; }
    float u_c[4];
#pragma unroll
    for (int nf = 0; nf < 4; ++nf) u_c[nf] = (float)(wn * 64 + nf * 16 + l15);

    for (int ic = 0; ic < 8; ++ic) {
        int chunk = gm * 8 + ic;          // = v row of image, 0..255
        int cb = chunk << 15;             // chunk*256*128 elems
        v4f acc[4][4];
#pragma unroll
        for (int mf = 0; mf < 4; ++mf)
#pragma unroll
            for (int nf = 0; nf < 4; ++nf) { v4f z = {0.f,0.f,0.f,0.f}; acc[mf][nf] = z; }

#pragma unroll
        for (int ks = 0; ks < 4; ++ks) {
            v8s ah[4], al2[4], bh[4], bl2[4];
#pragma unroll
            for (int mf = 0; mf < 4; ++mf) {
                ah[mf]  = *(const v8s*)(pAh + mf * 2048 + ks * 32);
                al2[mf] = *(const v8s*)(pAl + mf * 2048 + ks * 32);
            }
#pragma unroll
            for (int nf = 0; nf < 4; ++nf) {
                bh[nf]  = *(const v8s*)(pBh + cb + nf * 2048 + ks * 32);
                bl2[nf] = *(const v8s*)(pBl + cb + nf * 2048 + ks * 32);
            }
#pragma unroll
            for (int mf = 0; mf < 4; ++mf)
#pragma unroll
                for (int nf = 0; nf < 4; ++nf) {
                    acc[mf][nf] = __builtin_amdgcn_mfma_f32_16x16x32_bf16(ah[mf],  bh[nf],  acc[mf][nf], 0, 0, 0);
                    acc[mf][nf] = __builtin_amdgcn_mfma_f32_16x16x32_bf16(ah[mf],  bl2[nf], acc[mf][nf], 0, 0, 0);
                    acc[mf][nf] = __builtin_amdgcn_mfma_f32_16x16x32_bf16(al2[mf], bh[nf],  acc[mf][nf], 0, 0, 0);
                }
        }
        float vch = (float)chunk;
#pragma unroll
        for (int mf = 0; mf < 4; ++mf)
#pragma unroll
            for (int nf = 0; nf < 4; ++nf)
#pragma unroll
                for (int r = 0; r < 4; ++r) {
                    float e = exp2f(fmaf(acc[mf][nf][r], EXP2_SCALE, -EXP2_SCALE));
                    se[mf * 4 + r] += e;
                    seu[mf * 4 + r] = fmaf(e, u_c[nf], seu[mf * 4 + r]);
                    sev[mf * 4 + r] = fmaf(e, vch, sev[mf * 4 + r]);
                }
    }

#pragma unroll
    for (int s = 0; s < 16; ++s) {
        float a = se[s], u = seu[s], w = sev[s];
#pragma unroll
        for (int m = 1; m < 16; m <<= 1) {
            a += __shfl_xor(a, m, 64);
            u += __shfl_xor(u, m, 64);
            w += __shfl_xor(w, m, 64);
        }
        if (l15 == 0) {
            int mf = s >> 2, r = s & 3;
            int row = b * 512 + nt * 128 + wm * 64 + mf * 16 + l16 * 4 + r;
            float* P = part + ((size_t)(row * 32 + gm) * 4 + wn) * 3;
            P[0] = a; P[1] = u; P[2] = w;
        }
    }
}

// ---------------- reduce partials -> rowstats{invS,u,v}; write pseudo_coords ----
__global__ void __launch_bounds__(256) k_reduce(const float* __restrict__ part,
                                                float4* __restrict__ rows,
                                                float* __restrict__ out) {
    int r = blockIdx.x * 256 + threadIdx.x;  // 0..2047
    float S = 0.f, Su = 0.f, Sv = 0.f;
    for (int i = 0; i < 128; ++i) {
        const float* P = part + ((size_t)(r * 32) * 4 + i) * 3;
        S += P[0]; Su += P[1]; Sv += P[2];
    }
    float invS = 1.0f / S;
    float u = Su / S, v = Sv / S;
    rows[r] = make_float4(invS, u, v, 0.f);
    out[r * 2] = u;
    out[r * 2 + 1] = v;
}

// ---------------- pass B: recompute GEMM, write p = e * invS to soft_match_vals ----
__global__ void __launch_bounds__(512, 2) k_pass_b(const unsigned short* __restrict__ Ahi,
                                                   const unsigned short* __restrict__ Alo,
                                                   const unsigned short* __restrict__ Bhi,
                                                   const unsigned short* __restrict__ Blo,
                                                   const float4* __restrict__ rows,
                                                   float* __restrict__ out) {
    int tid = threadIdx.x;
    int l = tid & 63, wid = tid >> 6;
    int wm = wid >> 2, wn = wid & 3;
    int l15 = l & 15, l16 = l >> 4;
    int slot = blockIdx.x >> 5, gm = blockIdx.x & 31;
    int b = slot >> 2, nt = slot & 3;
    int row0 = nt * 128 + wm * 64;
    int rowbase = b * 512 + row0;

    const unsigned short* pAh = Ahi + ((b * 512 + row0 + l15) * 128 + l16 * 8);
    const unsigned short* pAl = Alo + ((b * 512 + row0 + l15) * 128 + l16 * 8);
    const unsigned short* pBh = Bhi + ((b * 65536 + wn * 64 + l15) * 128 + l16 * 8);
    const unsigned short* pBl = Blo + ((b * 65536 + wn * 64 + l15) * 128 + l16 * 8);

    float invs[16];
    unsigned voff[16];
#pragma unroll
    for (int s = 0; s < 16; ++s) {
        int row = rowbase + (s >> 2) * 16 + l16 * 4 + (s & 3);
        invs[s] = rows[row].x;
        voff[s] = (unsigned)row * 65536u + (unsigned)(wn * 64 + l15);
    }
    float* osm = out + 6144;  // soft_match_vals offset

    for (int ic = 0; ic < 8; ++ic) {
        int chunk = gm * 8 + ic;
        int cb = chunk << 15;
        v4f acc[4][4];
#pragma unroll
        for (int mf = 0; mf < 4; ++mf)
#pragma unroll
            for (int nf = 0; nf < 4; ++nf) { v4f z = {0.f,0.f,0.f,0.f}; acc[mf][nf] = z; }

#pragma unroll
        for (int ks = 0; ks < 4; ++ks) {
            v8s ah[4], al2[4], bh[4], bl2[4];
#pragma unroll
            for (int mf = 0; mf < 4; ++mf) {
                ah[mf]  = *(const v8s*)(pAh + mf * 2048 + ks * 32);
                al2[mf] = *(const v8s*)(pAl + mf * 2048 + ks * 32);
            }
#pragma unroll
            for (int nf = 0; nf < 4; ++nf) {
                bh[nf]  = *(const v8s*)(pBh + cb + nf * 2048 + ks * 32);
                bl2[nf] = *(const v8s*)(pBl + cb + nf * 2048 + ks * 32);
            }
#pragma unroll
            for (int mf = 0; mf < 4; ++mf)
#pragma unroll
                for (int nf = 0; nf < 4; ++nf) {
                    acc[mf][nf] = __builtin_amdgcn_mfma_f32_16x16x32_bf16(ah[mf],  bh[nf],  acc[mf][nf], 0, 0, 0);
                    acc[mf][nf] = __builtin_amdgcn_mfma_f32_16x16x32_bf16(ah[mf],  bl2[nf], acc[mf][nf], 0, 0, 0);
                    acc[mf][nf] = __builtin_amdgcn_mfma_f32_16x16x32_bf16(al2[mf], bh[nf],  acc[mf][nf], 0, 0, 0);
                }
        }
        unsigned coff = (unsigned)(chunk << 8);  // chunk*256
#pragma unroll
        for (int mf = 0; mf < 4; ++mf)
#pragma unroll
            for (int nf = 0; nf < 4; ++nf)
#pragma unroll
                for (int r = 0; r < 4; ++r) {
                    float e = exp2f(fmaf(acc[mf][nf][r], EXP2_SCALE, -EXP2_SCALE));
                    osm[(size_t)(voff[mf * 4 + r] + coff + nf * 16)] = e * invs[mf * 4 + r];
                }
    }
}

// ---------------- bilinear sample + match weights ----
__global__ void __launch_bounds__(256) k_sample(const float* __restrict__ ksc,
                                                const float* __restrict__ sd,
                                                const float* __restrict__ dd,
                                                const float* __restrict__ srcN,
                                                const float4* __restrict__ rows,
                                                float* __restrict__ out) {
    int gw = blockIdx.x * 4 + (threadIdx.x >> 6);  // b*512+n
    int l = threadIdx.x & 63;
    int b = gw >> 9, n = gw & 511;
    float4 rs = rows[gw];
    float u = rs.y, v = rs.z;
    // exact ref formula sequence
    float un = 2.0f * u / 255.0f - 1.0f;
    float vn = 2.0f * v / 255.0f - 1.0f;
    float x = ((un + 1.0f) * 256.0f - 1.0f) * 0.5f;
    float y = ((vn + 1.0f) * 256.0f - 1.0f) * 0.5f;
    float x0f = floorf(x), y0f = floorf(y);
    int x0 = (int)x0f, y0 = (int)y0f;
    int x1 = x0 + 1, y1 = y0 + 1;
    float wx1 = x - x0f, wy1 = y - y0f;
    float wx0 = 1.0f - wx1, wy0 = 1.0f - wy1;
    float m00 = ((x0 >= 0) & (x0 <= 255) & (y0 >= 0) & (y0 <= 255)) ? 1.f : 0.f;
    float m10 = ((x1 >= 0) & (x1 <= 255) & (y0 >= 0) & (y0 <= 255)) ? 1.f : 0.f;
    float m01 = ((x0 >= 0) & (x0 <= 255) & (y1 >= 0) & (y1 <= 255)) ? 1.f : 0.f;
    float m11 = ((x1 >= 0) & (x1 <= 255) & (y1 >= 0) & (y1 <= 255)) ? 1.f : 0.f;
    int cx0 = min(max(x0, 0), 255), cx1 = min(max(x1, 0), 255);
    int cy0 = min(max(y0, 0), 255), cy1 = min(max(y1, 0), 255);
    int i00 = cy0 * 256 + cx0, i10 = cy0 * 256 + cx1;
    int i01 = cy1 * 256 + cx0, i11 = cy1 * 256 + cx1;
    float w00 = wx0 * wy0 * m00, w10 = wx1 * wy0 * m10;
    float w01 = wx0 * wy1 * m01, w11 = wx1 * wy1 * m11;

    const float* sdb = sd + (size_t)(2 * b + 1) * 65536;
    float ps = w00 * sdb[i00] + w10 * sdb[i10] + w01 * sdb[i01] + w11 * sdb[i11];

    const float* ddb = dd + (size_t)(2 * b + 1) * 128 * 65536;
    float dot = 0.f;
#pragma unroll
    for (int h = 0; h < 2; ++h) {
        int c = l + h * 64;
        const float* dc = ddb + (size_t)c * 65536;
        float pd = w00 * dc[i00] + w10 * dc[i10] + w01 * dc[i01] + w11 * dc[i11];
        dot += srcN[gw * 128 + c] * pd;
    }
#pragma unroll
    for (int m = 1; m < 64; m <<= 1) dot += __shfl_xor(dot, m, 64);
    if (l == 0) {
        float dms = dot / 128.0f;
        float sscore = ksc[(2 * b) * 512 + n];
        out[4096 + gw] = 0.5f * (dms + 1.0f) * sscore * ps;
    }
}

extern "C" void kernel_launch(void* const* d_in, const int* in_sizes, int n_in,
                              void* d_out, int out_size, void* d_ws, size_t ws_size,
                              hipStream_t stream) {
    const float* ksc = (const float*)d_in[0];  // (8,1,512)
    const float* kd  = (const float*)d_in[1];  // (8,128,512)
    const float* sd  = (const float*)d_in[2];  // (8,1,256,256)
    const float* dd  = (const float*)d_in[3];  // (8,128,256,256)
    float* out = (float*)d_out;                // coords(4096) | mw(2048) | sm(134217728)
    char* ws = (char*)d_ws;

    unsigned short* Ahi = (unsigned short*)(ws + O_AHI);
    unsigned short* Alo = (unsigned short*)(ws + O_ALO);
    float*          srcN = (float*)(ws + O_SRCN);
    unsigned short* Bhi = (unsigned short*)(ws + O_BHI);
    unsigned short* Blo = (unsigned short*)(ws + O_BLO);
    float*          part = (float*)(ws + O_PART);
    float4*         rows = (float4*)(ws + O_ROWS);

    k_prep_src<<<512, 256, 0, stream>>>(kd, srcN, Ahi, Alo);
    k_prep_tgt<<<1024, 256, 0, stream>>>(dd, Bhi, Blo);
    k_pass_a<<<512, 512, 0, stream>>>(Ahi, Alo, Bhi, Blo, part);
    k_reduce<<<8, 256, 0, stream>>>(part, rows, out);
    k_pass_b<<<512, 512, 0, stream>>>(Ahi, Alo, Bhi, Blo, rows, out);
    k_sample<<<512, 256, 0, stream>>>(ksc, sd, dd, srcN, rows, out);
}

// Round 2
// 478.070 us; speedup vs baseline: 1.4808x; 1.4808x over previous
//
#include <hip/hip_runtime.h>

// SoftmaxMatcher on MI355X — round 2.
// GEMM passes rebuilt as m97-style LDS-staged 128x128 tiles:
//   K_ext = 384 = [Ahi*Bhi | Ahi*Blo | Alo*Bhi] (3-term bf16 split ~ f32 acc)
//   global_load_lds(16B) staging, XOR-swizzled granules, double buffer,
//   grid 8192 blocks (32/CU). MFMA operands swapped (pixels = operand 1)
//   so acc regs run along m -> pass_b stores via LDS-transposed 512B rows.

typedef short  v8s __attribute__((ext_vector_type(8)));
typedef unsigned short v8u __attribute__((ext_vector_type(8)));
typedef float  v4f __attribute__((ext_vector_type(4)));

#define EXP2_SCALE 144.269504088896f   // 1/(0.01*ln2)

// ---- workspace layout (bytes) ----
static const size_t O_AHI  = 0;                        // ushort[2048*128]
static const size_t O_ALO  = O_AHI  + 262144ull*2;
static const size_t O_SRCN = O_ALO  + 262144ull*2;     // float[2048*128]
static const size_t O_BHI  = O_SRCN + 262144ull*4;     // ushort[262144*128] 64MB
static const size_t O_BLO  = O_BHI  + 33554432ull*2;   // 64MB
static const size_t O_PART = O_BLO  + 33554432ull*2;   // float2[2048*512]   8MB
static const size_t O_ROWS = O_PART + 2048ull*512*8;   // float4[2048]

static __device__ inline unsigned short f2bf(float x) {
    unsigned u = __float_as_uint(x);
    u = u + 0x7FFFu + ((u >> 16) & 1u);   // RNE
    return (unsigned short)(u >> 16);
}
static __device__ inline float bf2f(unsigned short h) {
    return __uint_as_float(((unsigned)h) << 16);
}

__device__ __forceinline__ void gl_lds16(const void* g, void* l) {
    auto gp = (const __attribute__((address_space(1))) unsigned int*)(uintptr_t)g;
    auto lp = (__attribute__((address_space(3))) unsigned int*)(uintptr_t)l;
    __builtin_amdgcn_global_load_lds(gp, lp, 16, 0, 0);
}

// ---------------- prep: normalize src keypoint descs, bf16 hi/lo, [row][k] ----
__global__ void __launch_bounds__(256) k_prep_src(const float* __restrict__ kd,
                                                  float* __restrict__ srcN,
                                                  unsigned short* __restrict__ Ahi,
                                                  unsigned short* __restrict__ Alo) {
    int gw = blockIdx.x * 4 + (threadIdx.x >> 6);  // 0..2047 = b*512+n
    int l  = threadIdx.x & 63;
    int b  = gw >> 9, n = gw & 511;
    const float* base = kd + (size_t)(2 * b) * 128 * 512;
    float x0 = base[l * 512 + n];
    float x1 = base[(l + 64) * 512 + n];
    float ss = x0 * x0 + x1 * x1;
#pragma unroll
    for (int m = 1; m < 64; m <<= 1) ss += __shfl_xor(ss, m, 64);
    float inv = 1.0f / fmaxf(sqrtf(ss), 1e-12f);
    float xn0 = x0 * inv, xn1 = x1 * inv;
    int ob = gw * 128;
    srcN[ob + l] = xn0;  srcN[ob + l + 64] = xn1;
    unsigned short h0 = f2bf(xn0), h1 = f2bf(xn1);
    Ahi[ob + l] = h0;        Ahi[ob + l + 64] = h1;
    Alo[ob + l] = f2bf(xn0 - bf2f(h0));
    Alo[ob + l + 64] = f2bf(xn1 - bf2f(h1));
}

// ---------------- prep: normalize tgt dense descs, transpose to [m][k], hi/lo ----
__global__ void __launch_bounds__(256, 2) k_prep_tgt(const float* __restrict__ dd,
                                                     unsigned short* __restrict__ Bhi,
                                                     unsigned short* __restrict__ Blo) {
    int t = blockIdx.x * 256 + threadIdx.x;   // 0..262143
    int b = t >> 16;
    int p = t & 65535;
    const float* src = dd + (size_t)(2 * b + 1) * 128 * 65536 + p;
    float v[128];
    float ss = 0.f;
#pragma unroll
    for (int c = 0; c < 128; ++c) { float x = src[(size_t)c * 65536]; v[c] = x; ss += x * x; }
    float inv = 1.0f / fmaxf(sqrtf(ss), 1e-12f);
    size_t ob = (size_t)t * 128;
#pragma unroll
    for (int c8 = 0; c8 < 16; ++c8) {
        v8u h8, l8;
#pragma unroll
        for (int j = 0; j < 8; ++j) {
            float xn = v[c8 * 8 + j] * inv;
            unsigned short h = f2bf(xn);
            h8[j] = h;
            l8[j] = f2bf(xn - bf2f(h));
        }
        *(v8u*)(Bhi + ob + c8 * 8) = h8;
        *(v8u*)(Blo + ob + c8 * 8) = l8;
    }
}

// ---------------- fused GEMM (128x128 tile, K_ext=384, LDS staged) ----------
// MODE 0: per-(row, mtile) partials {sum e, sum e*m_local}
// MODE 1: write p = e * invS[row] to soft_match_vals
// grid (512 mt, 4 ny, 4 b), 256 threads = 4 waves (wm = w&1 m-half, wn = w>>1 n-half)
template <int MODE>
__global__ void __launch_bounds__(256, 2) k_gemm(const unsigned short* __restrict__ Ahi,
                                                 const unsigned short* __restrict__ Alo,
                                                 const unsigned short* __restrict__ Bhi,
                                                 const unsigned short* __restrict__ Blo,
                                                 const float4* __restrict__ rows,
                                                 float2* __restrict__ part,
                                                 float* __restrict__ osm) {
    __shared__ v4f ldsbuf[4096];           // 64 KB: 2 x (Kp 16K + Px 16K); aliased by epilogues
    char* lds = (char*)ldsbuf;

    const int tid = threadIdx.x;
    const int l = tid & 63, w = tid >> 6;
    const int wm = w & 1, wn = w >> 1;
    const int l15 = l & 15, l16 = l >> 4;
    const int mt = blockIdx.x, ny = blockIdx.y, b = blockIdx.z;

    const size_t kprow0 = (size_t)(b * 512 + ny * 128) * 128;   // elem offset into Ahi/Alo
    const size_t pxrow0 = (size_t)(b * 65536 + mt * 128) * 128; // elem offset into Bhi/Blo

    // staging slots: 1024 granules (16B) per tile, 4 per thread
    int soff[4], sdst[4];
#pragma unroll
    for (int i = 0; i < 4; ++i) {
        int s = tid + i * 256;
        int rl = s >> 3, g = s & 7;
        soff[i] = rl * 128 + ((g ^ (rl & 7)) << 3);   // pre-swizzled global elem offset
        sdst[i] = s << 4;                             // linear LDS byte offset
    }

    v4f acc[4][4];
#pragma unroll
    for (int mf = 0; mf < 4; ++mf)
#pragma unroll
        for (int nf = 0; nf < 4; ++nf) { v4f z = {0.f, 0.f, 0.f, 0.f}; acc[mf][nf] = z; }

    // K-step kb: term t=kb>>1 -> {Ah*Bh, Ah*Bl, Al*Bh}; k_off=(kb&1)*64
#define STAGE(kb, buf)                                                              \
    {                                                                               \
        const unsigned short* kp = (((kb) < 4) ? Ahi : Alo) + kprow0 + (((kb) & 1) << 6); \
        const unsigned short* px = ((((kb) >> 1) == 1) ? Blo : Bhi) + pxrow0 + (((kb) & 1) << 6); \
        char* base = lds + (buf) * 32768;                                           \
        _Pragma("unroll")                                                           \
        for (int i = 0; i < 4; ++i) {                                               \
            gl_lds16(kp + soff[i], base + sdst[i]);                                 \
            gl_lds16(px + soff[i], base + 16384 + sdst[i]);                         \
        }                                                                           \
    }

    STAGE(0, 0);
    __syncthreads();
    int buf = 0;
    for (int kb = 0; kb < 6; ++kb) {
        if (kb < 5) STAGE(kb + 1, buf ^ 1);
        const char* kp = lds + buf * 32768;
        const char* px = kp + 16384;
#pragma unroll
        for (int ks = 0; ks < 2; ++ks) {
            v8s af[4], bf[4];
#pragma unroll
            for (int mf = 0; mf < 4; ++mf) {
                int r = wm * 64 + mf * 16 + l15;
                int g = ((ks << 2) | l16) ^ (r & 7);
                af[mf] = *(const v8s*)(px + r * 128 + (g << 4));
            }
#pragma unroll
            for (int nf = 0; nf < 4; ++nf) {
                int r = wn * 64 + nf * 16 + l15;
                int g = ((ks << 2) | l16) ^ (r & 7);
                bf[nf] = *(const v8s*)(kp + r * 128 + (g << 4));
            }
#pragma unroll
            for (int mf = 0; mf < 4; ++mf)
#pragma unroll
                for (int nf = 0; nf < 4; ++nf)
                    acc[mf][nf] = __builtin_amdgcn_mfma_f32_16x16x32_bf16(af[mf], bf[nf], acc[mf][nf], 0, 0, 0);
        }
        __syncthreads();
        buf ^= 1;
    }
#undef STAGE
    // output frag: row = m = (l>>4)*4+reg (+16*mf+64*wm), col = n = l&15 (+16*nf+64*wn)

    if (MODE == 0) {
        float sS[4], sM[4];
#pragma unroll
        for (int nf = 0; nf < 4; ++nf) { sS[nf] = 0.f; sM[nf] = 0.f; }
#pragma unroll
        for (int mf = 0; mf < 4; ++mf) {
            float mbase = (float)(wm * 64 + mf * 16 + l16 * 4);
#pragma unroll
            for (int nf = 0; nf < 4; ++nf)
#pragma unroll
                for (int r = 0; r < 4; ++r) {
                    float e = __builtin_amdgcn_exp2f(fmaf(acc[mf][nf][r], EXP2_SCALE, -EXP2_SCALE));
                    sS[nf] += e;
                    sM[nf] = fmaf(e, mbase + (float)r, sM[nf]);
                }
        }
#pragma unroll
        for (int nf = 0; nf < 4; ++nf) {   // reduce across l16 groups
            sS[nf] += __shfl_xor(sS[nf], 16, 64); sS[nf] += __shfl_xor(sS[nf], 32, 64);
            sM[nf] += __shfl_xor(sM[nf], 16, 64); sM[nf] += __shfl_xor(sM[nf], 32, 64);
        }
        float* red = (float*)lds;          // [4 w][4 nf][16 l15][2]
        if (l < 16) {
#pragma unroll
            for (int nf = 0; nf < 4; ++nf) {
                red[((w * 4 + nf) * 16 + l15) * 2 + 0] = sS[nf];
                red[((w * 4 + nf) * 16 + l15) * 2 + 1] = sM[nf];
            }
        }
        __syncthreads();
        // combine wm halves: 256 thr = wn(2) x nf(4) x l15(16) x q(2)
        int q = tid & 1, p15 = (tid >> 1) & 15, pnf = (tid >> 5) & 3, pwn = tid >> 7;
        float vs = red[(((pwn * 2 + 0) * 4 + pnf) * 16 + p15) * 2 + q]
                 + red[(((pwn * 2 + 1) * 4 + pnf) * 16 + p15) * 2 + q];
        int rowg = b * 512 + ny * 128 + pwn * 64 + pnf * 16 + p15;
        ((float*)part)[((size_t)rowg * 512 + mt) * 2 + q] = vs;
    } else {
        float invs[4];
#pragma unroll
        for (int nf = 0; nf < 4; ++nf)
            invs[nf] = rows[b * 512 + ny * 128 + wn * 64 + nf * 16 + l15].x;
        // write p tile into LDS [128 n][128 m] f32, granule-swizzled
#pragma unroll
        for (int mf = 0; mf < 4; ++mf) {
            int mloc = wm * 64 + mf * 16 + l16 * 4;
#pragma unroll
            for (int nf = 0; nf < 4; ++nf) {
                int nloc = wn * 64 + nf * 16 + l15;
                v4f pv;
#pragma unroll
                for (int r = 0; r < 4; ++r)
                    pv[r] = __builtin_amdgcn_exp2f(fmaf(acc[mf][nf][r], EXP2_SCALE, -EXP2_SCALE)) * invs[nf];
                int g = (mloc >> 2) ^ (nloc & 7);
                *(v4f*)(lds + nloc * 512 + (g << 4)) = pv;
            }
        }
        __syncthreads();
        // cooperative store: 512B contiguous per row
        size_t obase = (size_t)(b * 512 + ny * 128) * 65536 + (size_t)mt * 128;
        int g = tid & 31, rh = tid >> 5;
#pragma unroll
        for (int it = 0; it < 16; ++it) {
            int r = it * 8 + rh;
            v4f v = *(const v4f*)(lds + r * 512 + ((g ^ (r & 7)) << 4));
            *(v4f*)(osm + obase + (size_t)r * 65536 + (g << 2)) = v;
        }
    }
}

// ---------------- reduce partials -> rowstats{invS,u,v}; write pseudo_coords ----
__global__ void __launch_bounds__(256) k_reduce(const float2* __restrict__ part,
                                                float4* __restrict__ rows,
                                                float* __restrict__ out) {
    int r = blockIdx.x * 4 + (threadIdx.x >> 6);  // 0..2047
    int l = threadIdx.x & 63;
    float S = 0.f, Su = 0.f, Sv = 0.f;
#pragma unroll
    for (int i = 0; i < 8; ++i) {
        int mtv = l + i * 64;
        float2 p = part[(size_t)r * 512 + mtv];
        S += p.x;
        Su += (float)((mtv & 1) * 128) * p.x + p.y;
        Sv += (float)(mtv >> 1) * p.x;
    }
#pragma unroll
    for (int m = 1; m < 64; m <<= 1) {
        S += __shfl_xor(S, m, 64);
        Su += __shfl_xor(Su, m, 64);
        Sv += __shfl_xor(Sv, m, 64);
    }
    if (l == 0) {
        float invS = 1.0f / S;
        float u = Su * invS, v = Sv * invS;
        rows[r] = make_float4(invS, u, v, 0.f);
        out[r * 2] = u;
        out[r * 2 + 1] = v;
    }
}

// ---------------- bilinear sample + match weights ----
__global__ void __launch_bounds__(256) k_sample(const float* __restrict__ ksc,
                                                const float* __restrict__ sd,
                                                const float* __restrict__ dd,
                                                const float* __restrict__ srcN,
                                                const float4* __restrict__ rows,
                                                float* __restrict__ out) {
    int gw = blockIdx.x * 4 + (threadIdx.x >> 6);  // b*512+n
    int l = threadIdx.x & 63;
    int b = gw >> 9, n = gw & 511;
    float4 rs = rows[gw];
    float u = rs.y, v = rs.z;
    float un = 2.0f * u / 255.0f - 1.0f;
    float vn = 2.0f * v / 255.0f - 1.0f;
    float x = ((un + 1.0f) * 256.0f - 1.0f) * 0.5f;
    float y = ((vn + 1.0f) * 256.0f - 1.0f) * 0.5f;
    float x0f = floorf(x), y0f = floorf(y);
    int x0 = (int)x0f, y0 = (int)y0f;
    int x1 = x0 + 1, y1 = y0 + 1;
    float wx1 = x - x0f, wy1 = y - y0f;
    float wx0 = 1.0f - wx1, wy0 = 1.0f - wy1;
    float m00 = ((x0 >= 0) & (x0 <= 255) & (y0 >= 0) & (y0 <= 255)) ? 1.f : 0.f;
    float m10 = ((x1 >= 0) & (x1 <= 255) & (y0 >= 0) & (y0 <= 255)) ? 1.f : 0.f;
    float m01 = ((x0 >= 0) & (x0 <= 255) & (y1 >= 0) & (y1 <= 255)) ? 1.f : 0.f;
    float m11 = ((x1 >= 0) & (x1 <= 255) & (y1 >= 0) & (y1 <= 255)) ? 1.f : 0.f;
    int cx0 = min(max(x0, 0), 255), cx1 = min(max(x1, 0), 255);
    int cy0 = min(max(y0, 0), 255), cy1 = min(max(y1, 0), 255);
    int i00 = cy0 * 256 + cx0, i10 = cy0 * 256 + cx1;
    int i01 = cy1 * 256 + cx0, i11 = cy1 * 256 + cx1;
    float w00 = wx0 * wy0 * m00, w10 = wx1 * wy0 * m10;
    float w01 = wx0 * wy1 * m01, w11 = wx1 * wy1 * m11;

    const float* sdb = sd + (size_t)(2 * b + 1) * 65536;
    float ps = w00 * sdb[i00] + w10 * sdb[i10] + w01 * sdb[i01] + w11 * sdb[i11];

    const float* ddb = dd + (size_t)(2 * b + 1) * 128 * 65536;
    float dot = 0.f;
#pragma unroll
    for (int h = 0; h < 2; ++h) {
        int c = l + h * 64;
        const float* dc = ddb + (size_t)c * 65536;
        float pd = w00 * dc[i00] + w10 * dc[i10] + w01 * dc[i01] + w11 * dc[i11];
        dot += srcN[gw * 128 + c] * pd;
    }
#pragma unroll
    for (int m = 1; m < 64; m <<= 1) dot += __shfl_xor(dot, m, 64);
    if (l == 0) {
        float dms = dot / 128.0f;
        float sscore = ksc[(2 * b) * 512 + n];
        out[4096 + gw] = 0.5f * (dms + 1.0f) * sscore * ps;
    }
}

extern "C" void kernel_launch(void* const* d_in, const int* in_sizes, int n_in,
                              void* d_out, int out_size, void* d_ws, size_t ws_size,
                              hipStream_t stream) {
    const float* ksc = (const float*)d_in[0];  // (8,1,512)
    const float* kd  = (const float*)d_in[1];  // (8,128,512)
    const float* sd  = (const float*)d_in[2];  // (8,1,256,256)
    const float* dd  = (const float*)d_in[3];  // (8,128,256,256)
    float* out = (float*)d_out;                // coords(4096) | mw(2048) | sm(134217728)
    char* ws = (char*)d_ws;

    unsigned short* Ahi  = (unsigned short*)(ws + O_AHI);
    unsigned short* Alo  = (unsigned short*)(ws + O_ALO);
    float*          srcN = (float*)(ws + O_SRCN);
    unsigned short* Bhi  = (unsigned short*)(ws + O_BHI);
    unsigned short* Blo  = (unsigned short*)(ws + O_BLO);
    float2*         part = (float2*)(ws + O_PART);
    float4*         rows = (float4*)(ws + O_ROWS);
    float*          osm  = out + 6144;

    k_prep_src<<<512, 256, 0, stream>>>(kd, srcN, Ahi, Alo);
    k_prep_tgt<<<1024, 256, 0, stream>>>(dd, Bhi, Blo);
    k_gemm<0><<<dim3(512, 4, 4), 256, 0, stream>>>(Ahi, Alo, Bhi, Blo, rows, part, osm);
    k_reduce<<<512, 256, 0, stream>>>(part, rows, out);
    k_gemm<1><<<dim3(512, 4, 4), 256, 0, stream>>>(Ahi, Alo, Bhi, Blo, rows, part, osm);
    k_sample<<<512, 256, 0, stream>>>(ksc, sd, dd, srcN, rows, out);
}